// Round 1
// baseline (6337.849 us; speedup 1.0000x reference)
//
#include <hip/hip_runtime.h>
#include <hip/hip_bf16.h>

// LSTM T=512 B=32 IN=H=1024 L=2. fp32 in/out, bf16 MFMA internally.
// Round 1: pipelined per-step launches (layer0@t + layer1@t-1), K=2048 fused GEMM.

namespace {
constexpr int T_STEPS = 512;
constexpr int BATCH   = 32;
constexpr int HID     = 1024;
constexpr int G4H     = 4096;
constexpr int KCAT    = 2048;
constexpr int BH      = BATCH * HID;                 // 32768
constexpr size_t MEM_ELEMS = (size_t)T_STEPS * BH;   // 16,777,216

// workspace layout (bytes)
constexpr size_t OFF_W    = 0;
constexpr size_t SZ_W     = (size_t)2 * G4H * KCAT * 2;   // bf16 W_cat  33.55 MB
constexpr size_t OFF_BIAS = OFF_W + SZ_W;                 // f32 [2][4096]
constexpr size_t SZ_BIAS  = (size_t)2 * G4H * 4;
constexpr size_t OFF_H0PP = OFF_BIAS + SZ_BIAS;           // bf16 [2][32][1024]
constexpr size_t SZ_PP    = (size_t)2 * BH * 2;
constexpr size_t OFF_H1PP = OFF_H0PP + SZ_PP;
constexpr size_t WS_NEED  = OFF_H1PP + SZ_PP;             // ~33.85 MB
}

typedef __attribute__((ext_vector_type(8))) short short8;
typedef __attribute__((ext_vector_type(4))) float f32x4;
typedef unsigned short u16;

__device__ inline unsigned short f2bf(float x) {
  unsigned u = __builtin_bit_cast(unsigned, x);
  u += 0x7fffu + ((u >> 16) & 1u);          // RNE
  return (unsigned short)(u >> 16);
}
__device__ inline float sigm(float x) { return 1.0f / (1.0f + __expf(-x)); }

// ---------------- conversion: W_cat bf16, bias sum, h0 -> pingpong[1] ----------------
__global__ void cvt_kernel(const float* __restrict__ Wih, const float* __restrict__ Whh,
                           const float* __restrict__ bih, const float* __restrict__ bhh,
                           const float* __restrict__ h0,
                           u16* __restrict__ Wcat, float* __restrict__ bias,
                           u16* __restrict__ h0pp, u16* __restrict__ h1pp) {
  size_t idx = (size_t)blockIdx.x * blockDim.x + threadIdx.x;
  size_t stride = (size_t)gridDim.x * blockDim.x;
  const size_t NW = (size_t)2 * G4H * KCAT;
  for (size_t i = idx; i < NW; i += stride) {
    size_t ln = i >> 11;                 // l*4096 + n
    int k = (int)(i & 2047);
    float v = (k < HID) ? Wih[ln * HID + k] : Whh[ln * HID + (k - HID)];
    Wcat[i] = f2bf(v);
  }
  for (size_t i = idx; i < (size_t)2 * G4H; i += stride) bias[i] = bih[i] + bhh[i];
  for (size_t i = idx; i < (size_t)2 * BH; i += stride) {
    unsigned short v = f2bf(h0[i]);
    if (i < (size_t)BH) h0pp[(size_t)BH + i] = v;       // t=0 reads buffer 1
    else                h1pp[(size_t)BH + (i - BH)] = v;
  }
}

// ---------------- main recurrent step (both layers pipelined) ----------------
__global__ __launch_bounds__(256) void lstm_step(
    const float* __restrict__ input, const u16* __restrict__ Wcat,
    const float* __restrict__ bias, u16* __restrict__ h0pp, u16* __restrict__ h1pp,
    const float* __restrict__ c0, float* __restrict__ out, int t)
{
  const bool is_l1 = (blockIdx.x >= 128);
  const int s = is_l1 ? (t - 1) : t;
  if (s < 0 || s >= T_STEPS) return;
  const int l = is_l1 ? 1 : 0;
  const int cb = blockIdx.x & 127;
  const int j0 = cb << 3;                 // 8 hidden units per block
  const int tid = threadIdx.x;
  const int lane = tid & 63;
  const int wid = tid >> 6;
  const int l15 = lane & 15;
  const int lq  = lane >> 4;
  const int koff = lq << 3;
  const int k0 = wid << 9;                // wave K-slice: 512

  // B frags: n-tile0 = {i,f}, n-tile1 = {g,o} rows of W_cat
  const int row0 = (l15 < 8) ? (j0 + l15) : (HID + j0 + l15 - 8);
  const int row1 = (l15 < 8) ? (2 * HID + j0 + l15) : (3 * HID + j0 + l15 - 8);
  const u16* bp0 = Wcat + ((size_t)l * G4H + row0) * KCAT + k0 + koff;
  const u16* bp1 = Wcat + ((size_t)l * G4H + row1) * KCAT + k0 + koff;

  f32x4 acc00 = {0.f, 0.f, 0.f, 0.f};
  f32x4 acc01 = acc00, acc10 = acc00, acc11 = acc00;

  const bool a_f32 = (!is_l1) && (wid < 2);   // layer0 x-part comes from fp32 input
  if (a_f32) {
    const float* base = input + (size_t)s * BH + k0 + koff;
    const float* af0 = base + (size_t)l15 * HID;
    const float* af1 = base + (size_t)(16 + l15) * HID;
    #pragma unroll 4
    for (int ks = 0; ks < 16; ++ks) {
      const int kk = ks * 32;
      short8 b0 = *(const short8*)(bp0 + kk);
      short8 b1 = *(const short8*)(bp1 + kk);
      float4 x0 = *(const float4*)(af0 + kk);
      float4 x1 = *(const float4*)(af0 + kk + 4);
      float4 y0 = *(const float4*)(af1 + kk);
      float4 y1 = *(const float4*)(af1 + kk + 4);
      short8 a0, a1;
      a0[0] = (short)f2bf(x0.x); a0[1] = (short)f2bf(x0.y);
      a0[2] = (short)f2bf(x0.z); a0[3] = (short)f2bf(x0.w);
      a0[4] = (short)f2bf(x1.x); a0[5] = (short)f2bf(x1.y);
      a0[6] = (short)f2bf(x1.z); a0[7] = (short)f2bf(x1.w);
      a1[0] = (short)f2bf(y0.x); a1[1] = (short)f2bf(y0.y);
      a1[2] = (short)f2bf(y0.z); a1[3] = (short)f2bf(y0.w);
      a1[4] = (short)f2bf(y1.x); a1[5] = (short)f2bf(y1.y);
      a1[6] = (short)f2bf(y1.z); a1[7] = (short)f2bf(y1.w);
      acc00 = __builtin_amdgcn_mfma_f32_16x16x32_bf16(a0, b0, acc00, 0, 0, 0);
      acc01 = __builtin_amdgcn_mfma_f32_16x16x32_bf16(a0, b1, acc01, 0, 0, 0);
      acc10 = __builtin_amdgcn_mfma_f32_16x16x32_bf16(a1, b0, acc10, 0, 0, 0);
      acc11 = __builtin_amdgcn_mfma_f32_16x16x32_bf16(a1, b1, acc11, 0, 0, 0);
    }
  } else {
    const u16* src; int ksrc;
    if (!is_l1)       { src = h0pp + (((s + 1) & 1) * BH); ksrc = k0 - HID; }  // l0 h-part
    else if (wid < 2) { src = h0pp + ((s & 1) * BH);       ksrc = k0;       }  // l1 x-part
    else              { src = h1pp + (((s + 1) & 1) * BH); ksrc = k0 - HID; }  // l1 h-part
    const u16* ab0 = src + (size_t)l15 * HID + ksrc + koff;
    const u16* ab1 = src + (size_t)(16 + l15) * HID + ksrc + koff;
    #pragma unroll 4
    for (int ks = 0; ks < 16; ++ks) {
      const int kk = ks * 32;
      short8 b0 = *(const short8*)(bp0 + kk);
      short8 b1 = *(const short8*)(bp1 + kk);
      short8 a0 = *(const short8*)(ab0 + kk);
      short8 a1 = *(const short8*)(ab1 + kk);
      acc00 = __builtin_amdgcn_mfma_f32_16x16x32_bf16(a0, b0, acc00, 0, 0, 0);
      acc01 = __builtin_amdgcn_mfma_f32_16x16x32_bf16(a0, b1, acc01, 0, 0, 0);
      acc10 = __builtin_amdgcn_mfma_f32_16x16x32_bf16(a1, b0, acc10, 0, 0, 0);
      acc11 = __builtin_amdgcn_mfma_f32_16x16x32_bf16(a1, b1, acc11, 0, 0, 0);
    }
  }

  // cross-wave K reduction via LDS
  __shared__ float red[4][2][2][256];
  #pragma unroll
  for (int r = 0; r < 4; ++r) {
    red[wid][0][0][lane * 4 + r] = acc00[r];
    red[wid][0][1][lane * 4 + r] = acc01[r];
    red[wid][1][0][lane * 4 + r] = acc10[r];
    red[wid][1][1][lane * 4 + r] = acc11[r];
  }
  __syncthreads();

  // elementwise cell update: one (m, jj) per thread
  const int m  = tid >> 3;
  const int jj = tid & 7;
  const int j  = j0 + jj;
  const int mt = m >> 4;
  const int mm = m & 15;
  const int rr = mm & 3;
  const int lbase = (mm >> 2) << 4;

  float g4[4];
  #pragma unroll
  for (int gate = 0; gate < 4; ++gate) {
    const int nt = gate >> 1;
    const int nn = ((gate & 1) << 3) + jj;
    const int li = (lbase | nn) * 4 + rr;
    float v = red[0][mt][nt][li] + red[1][mt][nt][li] +
              red[2][mt][nt][li] + red[3][mt][nt][li];
    g4[gate] = v + bias[l * G4H + gate * HID + j];
  }

  float* hT     = out + MEM_ELEMS;                      // [2][32][1024]
  float* cstate = out + MEM_ELEMS + 2 * (size_t)BH;     // cT region doubles as running c
  const size_t cidx = (size_t)l * BH + (size_t)m * HID + j;
  const float c_old = (s == 0) ? c0[cidx] : cstate[cidx];
  const float ig = sigm(g4[0]);
  const float fg = sigm(g4[1]);
  const float gg = tanhf(g4[2]);
  const float og = sigm(g4[3]);
  const float c_new = fg * c_old + ig * gg;
  const float h_new = og * tanhf(c_new);
  cstate[cidx] = c_new;
  u16* ppw = (is_l1 ? h1pp : h0pp) + (s & 1) * BH;
  ppw[m * HID + j] = f2bf(h_new);
  if (is_l1) out[(size_t)s * BH + (size_t)m * HID + j] = h_new;   // memorys
  if (s == T_STEPS - 1) hT[cidx] = h_new;
}

// ---------------- fp32 fallback (only if ws too small for bf16 weights) ----------------
__global__ void fb_init(const float* __restrict__ h0, float* __restrict__ h0ppf,
                        float* __restrict__ h1ppf) {
  int i = blockIdx.x * blockDim.x + threadIdx.x;
  if (i < BH) h0ppf[BH + i] = h0[i];
  else if (i < 2 * BH) h1ppf[BH + (i - BH)] = h0[i];
}

__global__ __launch_bounds__(256) void fb_step(
    const float* __restrict__ input, const float* __restrict__ Wih,
    const float* __restrict__ Whh, const float* __restrict__ bih,
    const float* __restrict__ bhh, float* __restrict__ h0ppf, float* __restrict__ h1ppf,
    const float* __restrict__ c0, float* __restrict__ out, int t)
{
  const bool is_l1 = (blockIdx.x >= 128);
  const int s = is_l1 ? (t - 1) : t;
  if (s < 0 || s >= T_STEPS) return;
  const int l = is_l1 ? 1 : 0;
  const int cb = blockIdx.x & 127, j0 = cb << 3, tid = threadIdx.x;
  const float* xsrc = is_l1 ? (h0ppf + (s & 1) * BH) : (input + (size_t)s * BH);
  const float* hsrc = (is_l1 ? h1ppf : h0ppf) + (((s + 1) & 1) * BH);
  const int c = tid & 31, mg = tid >> 5;
  const int gate = c >> 3, jc = c & 7;
  const int row = gate * HID + j0 + jc;
  const float* wi = Wih + ((size_t)l * G4H + row) * HID;
  const float* wh = Whh + ((size_t)l * G4H + row) * HID;
  const float* x0 = xsrc + (size_t)(mg * 4 + 0) * HID;
  const float* x1 = xsrc + (size_t)(mg * 4 + 1) * HID;
  const float* x2 = xsrc + (size_t)(mg * 4 + 2) * HID;
  const float* x3 = xsrc + (size_t)(mg * 4 + 3) * HID;
  const float* h0p = hsrc + (size_t)(mg * 4 + 0) * HID;
  const float* h1p = hsrc + (size_t)(mg * 4 + 1) * HID;
  const float* h2p = hsrc + (size_t)(mg * 4 + 2) * HID;
  const float* h3p = hsrc + (size_t)(mg * 4 + 3) * HID;
  float a0 = 0, a1 = 0, a2 = 0, a3 = 0;
  for (int k = 0; k < HID; ++k) {
    float wa = wi[k], wb = wh[k];
    a0 += x0[k] * wa + h0p[k] * wb;
    a1 += x1[k] * wa + h1p[k] * wb;
    a2 += x2[k] * wa + h2p[k] * wb;
    a3 += x3[k] * wa + h3p[k] * wb;
  }
  __shared__ float gl[32][32];
  const float bsum = bih[l * G4H + row] + bhh[l * G4H + row];
  gl[mg * 4 + 0][c] = a0 + bsum;
  gl[mg * 4 + 1][c] = a1 + bsum;
  gl[mg * 4 + 2][c] = a2 + bsum;
  gl[mg * 4 + 3][c] = a3 + bsum;
  __syncthreads();
  const int m = tid >> 3, jj = tid & 7, j = j0 + jj;
  float g4[4];
  #pragma unroll
  for (int g = 0; g < 4; ++g) g4[g] = gl[m][g * 8 + jj];
  float* hT = out + MEM_ELEMS;
  float* cstate = out + MEM_ELEMS + 2 * (size_t)BH;
  const size_t cidx = (size_t)l * BH + (size_t)m * HID + j;
  const float c_old = (s == 0) ? c0[cidx] : cstate[cidx];
  const float ig = sigm(g4[0]);
  const float fg = sigm(g4[1]);
  const float gg = tanhf(g4[2]);
  const float og = sigm(g4[3]);
  const float c_new = fg * c_old + ig * gg;
  const float h_new = og * tanhf(c_new);
  cstate[cidx] = c_new;
  float* ppw = (is_l1 ? h1ppf : h0ppf) + (s & 1) * BH;
  ppw[m * HID + j] = h_new;
  if (is_l1) out[(size_t)s * BH + (size_t)m * HID + j] = h_new;
  if (s == T_STEPS - 1) hT[cidx] = h_new;
}

extern "C" void kernel_launch(void* const* d_in, const int* in_sizes, int n_in,
                              void* d_out, int out_size, void* d_ws, size_t ws_size,
                              hipStream_t stream) {
  const float* input = (const float*)d_in[0];
  const float* h0    = (const float*)d_in[1];
  const float* c0    = (const float*)d_in[2];
  const float* Wih   = (const float*)d_in[3];
  const float* Whh   = (const float*)d_in[4];
  const float* bih   = (const float*)d_in[5];
  const float* bhh   = (const float*)d_in[6];
  float* out = (float*)d_out;
  char* ws = (char*)d_ws;

  if (ws_size >= WS_NEED) {
    u16*   Wcat = (u16*)(ws + OFF_W);
    float* bias = (float*)(ws + OFF_BIAS);
    u16*   h0pp = (u16*)(ws + OFF_H0PP);
    u16*   h1pp = (u16*)(ws + OFF_H1PP);
    cvt_kernel<<<4096, 256, 0, stream>>>(Wih, Whh, bih, bhh, h0, Wcat, bias, h0pp, h1pp);
    for (int t = 0; t <= T_STEPS; ++t)
      lstm_step<<<256, 256, 0, stream>>>(input, Wcat, bias, h0pp, h1pp, c0, out, t);
  } else {
    float* h0ppf = (float*)ws;                          // [2][BH] f32
    float* h1ppf = (float*)(ws + (size_t)2 * BH * 4);   // [2][BH] f32
    fb_init<<<256, 256, 0, stream>>>(h0, h0ppf, h1ppf);
    for (int t = 0; t <= T_STEPS; ++t)
      fb_step<<<256, 256, 0, stream>>>(input, Wih, Whh, bih, bhh, h0ppf, h1ppf, c0, out, t);
  }
}